// Round 1
// baseline (590.673 us; speedup 1.0000x reference)
//
#include <hip/hip_runtime.h>
#include <math.h>

#define NA_ 128
#define F_ 256
#define VBS_ 128

__global__ __launch_bounds__(256, 1) void attn_fused(
    const float* __restrict__ a,      // [N, NA]
    const float* __restrict__ prior,  // [N, F]
    const float* __restrict__ W,      // [F, NA]
    const float* __restrict__ bias,   // [F]
    const float* __restrict__ bnw,    // [F]
    const float* __restrict__ bnb,    // [F]
    float* __restrict__ out_m,        // [N, F]
    float* __restrict__ out_np)       // [N, F]
{
    __shared__ float zbuf[VBS_ * F_];     // 128 KB: x, then z
    __shared__ float astage[32 * NA_];    // 16 KB: quarter of a-chunk
    __shared__ float tau_s[VBS_];
    __shared__ float scale_s[F_];
    __shared__ float shift_s[F_];
    __shared__ float srt[F_];             // slow-path sort buffer
    __shared__ int nflag;

    const int tid = threadIdx.x;
    const int f = tid;                    // feature owned by this thread
    const int chunk = blockIdx.x;
    const size_t rowbase = (size_t)chunk * VBS_;

    if (tid == 0) nflag = 0;

    // ---- W row into registers (128 VGPRs), bias
    float4 w4[NA_ / 4];
    {
        const float4* wrow = reinterpret_cast<const float4*>(W + (size_t)f * NA_);
        #pragma unroll
        for (int i = 0; i < NA_ / 4; ++i) w4[i] = wrow[i];
    }
    const float bf = bias[f];

    // ---- GEMM: x[r][f] = a[r][:] . W[f][:] + b[f], in 4 row-quarters
    for (int q = 0; q < 4; ++q) {
        __syncthreads();
        {
            const float4* ag = reinterpret_cast<const float4*>(a + (rowbase + (size_t)q * 32) * NA_);
            float4* as4 = reinterpret_cast<float4*>(astage);
            for (int idx = tid; idx < 32 * NA_ / 4; idx += 256) as4[idx] = ag[idx];
        }
        __syncthreads();
        for (int rr = 0; rr < 32; ++rr) {
            const float4* arow = reinterpret_cast<const float4*>(astage + rr * NA_);
            float acc0 = bf, acc1 = 0.f, acc2 = 0.f, acc3 = 0.f;
            #pragma unroll
            for (int kk = 0; kk < NA_ / 4; ++kk) {
                float4 av = arow[kk];
                acc0 = fmaf(av.x, w4[kk].x, acc0);
                acc1 = fmaf(av.y, w4[kk].y, acc1);
                acc2 = fmaf(av.z, w4[kk].z, acc2);
                acc3 = fmaf(av.w, w4[kk].w, acc3);
            }
            zbuf[(q * 32 + rr) * F_ + f] = (acc0 + acc1) + (acc2 + acc3);
        }
    }
    __syncthreads();

    // ---- BN stats per feature (within-thread over 128 rows)
    {
        float s0 = 0, s1 = 0, s2 = 0, s3 = 0, q0 = 0, q1 = 0, q2 = 0, q3 = 0;
        for (int r = 0; r < VBS_; r += 4) {
            float v0 = zbuf[(r + 0) * F_ + f];
            float v1 = zbuf[(r + 1) * F_ + f];
            float v2 = zbuf[(r + 2) * F_ + f];
            float v3 = zbuf[(r + 3) * F_ + f];
            s0 += v0; s1 += v1; s2 += v2; s3 += v3;
            q0 = fmaf(v0, v0, q0); q1 = fmaf(v1, v1, q1);
            q2 = fmaf(v2, v2, q2); q3 = fmaf(v3, v3, q3);
        }
        float sum = (s0 + s1) + (s2 + s3);
        float ss  = (q0 + q1) + (q2 + q3);
        float mean = sum * (1.0f / VBS_);
        float var  = ss * (1.0f / VBS_) - mean * mean;
        float rs = rsqrtf(var + 1e-5f) * bnw[f];
        scale_s[f] = rs;
        shift_s[f] = bnb[f] - mean * rs;
    }
    __syncthreads();

    // ---- normalize & multiply prior -> z (in zbuf), float4, 4 rows/iter
    {
        const int rsub = tid >> 6;        // wave id = row offset
        const int c4 = tid & 63;          // float4 column
        float4 sc = reinterpret_cast<const float4*>(scale_s)[c4];
        float4 sh = reinterpret_cast<const float4*>(shift_s)[c4];
        for (int i = 0; i < VBS_ / 4; ++i) {
            int r = i * 4 + rsub;
            float4 x4 = reinterpret_cast<float4*>(zbuf)[r * (F_ / 4) + c4];
            float4 p4 = reinterpret_cast<const float4*>(prior + (rowbase + r) * F_)[c4];
            float4 z;
            z.x = fmaf(x4.x, sc.x, sh.x) * p4.x;
            z.y = fmaf(x4.y, sc.y, sh.y) * p4.y;
            z.z = fmaf(x4.z, sc.z, sh.z) * p4.z;
            z.w = fmaf(x4.w, sc.w, sh.w) * p4.w;
            reinterpret_cast<float4*>(zbuf)[r * (F_ / 4) + c4] = z;
        }
    }
    __syncthreads();

    // ---- per-row sum & max; fast-path tau, flag rows needing full sort
    {
        const int wid = tid >> 6, lane = tid & 63;
        for (int r = wid * 32; r < wid * 32 + 32; ++r) {
            float v0 = zbuf[r * F_ + lane];
            float v1 = zbuf[r * F_ + lane + 64];
            float v2 = zbuf[r * F_ + lane + 128];
            float v3 = zbuf[r * F_ + lane + 192];
            float s = (v0 + v1) + (v2 + v3);
            float mx = fmaxf(fmaxf(v0, v1), fmaxf(v2, v3));
            #pragma unroll
            for (int d = 32; d > 0; d >>= 1) {
                s += __shfl_xor(s, d, 64);
                mx = fmaxf(mx, __shfl_xor(mx, d, 64));
            }
            if (lane == 0) {
                // C_{D-1}: 1 + 255*s_max - sum > 0  =>  k_z = 255, m_z = sum
                if (1.0f + 255.0f * mx - s > 0.0f) {
                    tau_s[r] = (s + 1.0f) * (1.0f / 255.0f);
                } else {
                    tau_s[r] = __int_as_float(0x7fc00000);   // NaN marker
                    atomicAdd(&nflag, 1);
                }
            }
        }
    }
    __syncthreads();

    // ---- slow path (faithful sorted algorithm) for flagged rows; block-uniform
    if (nflag > 0) {
        for (int r = 0; r < VBS_; ++r) {
            float tv = tau_s[r];
            bool bad = (tv != tv);
            if (!bad) continue;           // uniform: all threads read same LDS value
            if (tid == 0) {
                for (int i = 0; i < F_; ++i) srt[i] = zbuf[r * F_ + i];
                for (int i = 1; i < F_; ++i) {        // insertion sort ascending
                    float key = srt[i]; int j = i - 1;
                    while (j >= 0 && srt[j] > key) { srt[j + 1] = srt[j]; --j; }
                    srt[j + 1] = key;
                }
                float cs = 0.f; int kz = 0;
                for (int j = 0; j < F_; ++j) {
                    cs += srt[j];
                    if (1.0f + (float)j * srt[j] - cs > 0.0f) kz = j;  // last true j
                }
                float mz = 0.f;
                for (int j = 0; j <= kz; ++j) mz += srt[j];
                tau_s[r] = (mz + 1.0f) / (float)kz;   // kz==0 -> inf -> m=0 (matches clip)
            }
            __syncthreads();
        }
    }
    __syncthreads();

    // ---- outputs: m = relu(z - tau); new_prior = prior * (1.5 - m)
    {
        const int rsub = tid >> 6;
        const int c4 = tid & 63;
        for (int i = 0; i < VBS_ / 4; ++i) {
            int r = i * 4 + rsub;
            float tau = tau_s[r];
            float4 z4 = reinterpret_cast<float4*>(zbuf)[r * (F_ / 4) + c4];
            float4 p4 = reinterpret_cast<const float4*>(prior + (rowbase + r) * F_)[c4];
            float4 m4, n4;
            m4.x = fmaxf(z4.x - tau, 0.0f); n4.x = p4.x * (1.5f - m4.x);
            m4.y = fmaxf(z4.y - tau, 0.0f); n4.y = p4.y * (1.5f - m4.y);
            m4.z = fmaxf(z4.z - tau, 0.0f); n4.z = p4.z * (1.5f - m4.z);
            m4.w = fmaxf(z4.w - tau, 0.0f); n4.w = p4.w * (1.5f - m4.w);
            reinterpret_cast<float4*>(out_m + (rowbase + r) * F_)[c4] = m4;
            reinterpret_cast<float4*>(out_np + (rowbase + r) * F_)[c4] = n4;
        }
    }
}

extern "C" void kernel_launch(void* const* d_in, const int* in_sizes, int n_in,
                              void* d_out, int out_size, void* d_ws, size_t ws_size,
                              hipStream_t stream) {
    const float* a     = (const float*)d_in[0];
    const float* prior = (const float*)d_in[1];
    const float* W     = (const float*)d_in[2];
    const float* b     = (const float*)d_in[3];
    const float* bnw   = (const float*)d_in[4];
    const float* bnb   = (const float*)d_in[5];
    const int N = in_sizes[0] / NA_;
    const int nchunks = N / VBS_;
    float* out_m  = (float*)d_out;
    float* out_np = out_m + (size_t)N * F_;
    attn_fused<<<nchunks, 256, 0, stream>>>(a, prior, W, b, bnw, bnb, out_m, out_np);
}

// Round 2
// 140.349 us; speedup vs baseline: 4.2086x; 4.2086x over previous
//
#include <hip/hip_runtime.h>
#include <math.h>

#define NA_ 128
#define F_ 256
#define VBS_ 128
#define GAMMA_ 1.5f
#define EPS_ 1e-5f

typedef __attribute__((ext_vector_type(8))) short short8;
typedef __attribute__((ext_vector_type(4))) float f32x4;

static __device__ __forceinline__ unsigned f2bf(float f) {
    unsigned u = __float_as_uint(f);
    return (u + 0x7FFFu + ((u >> 16) & 1u)) >> 16;   // RNE bf16
}
static __device__ __forceinline__ float bflo(unsigned u) { return __uint_as_float(u << 16); }
static __device__ __forceinline__ float bfhi(unsigned u) { return __uint_as_float(u & 0xFFFF0000u); }

// ---------------- kernel 0: W f32 -> bf16 (one-time per call, 128 KB) ----------------
__global__ void k0_cvt_w(const float* __restrict__ W, unsigned short* __restrict__ Wb) {
    int i = blockIdx.x * 256 + threadIdx.x;          // 8192 groups of 4
    float4 v = reinterpret_cast<const float4*>(W)[i];
    uint2 o;
    o.x = f2bf(v.x) | (f2bf(v.y) << 16);
    o.y = f2bf(v.z) | (f2bf(v.w) << 16);
    reinterpret_cast<uint2*>(Wb)[i] = o;
}

// ---------------- kernel 1: MFMA GEMM (x = a @ W^T) + ghost-BN scale/shift ----------------
// block = one virtual-batch chunk (128 rows), 4 waves; wave w owns features [64w, 64w+64)
__global__ __launch_bounds__(256, 2) void k1_gemm_stats(
    const float* __restrict__ a, const unsigned short* __restrict__ Wb,
    const float* __restrict__ bnw, const float* __restrict__ bnb,
    unsigned short* __restrict__ xb,
    float* __restrict__ scale_g, float* __restrict__ shift_g)
{
    __shared__ unsigned short albuf[VBS_ * NA_];   // 32 KB bf16, XOR-swizzled 16B units
    const int tid = threadIdx.x;
    const int chunk = blockIdx.x;
    const size_t rowbase = (size_t)chunk * VBS_;

    // ---- stage a (f32) -> bf16 LDS, swizzle byte ^= ((row&7)<<4), 16B granularity
    #pragma unroll
    for (int i = 0; i < 8; ++i) {
        int seg = tid + 256 * i;                   // 2048 segs of 8 elems
        int row = seg >> 4, ks = seg & 15;
        const float4* g = reinterpret_cast<const float4*>(a + (rowbase + row) * NA_ + ks * 8);
        float4 v0 = g[0], v1 = g[1];
        uint4 pk;
        pk.x = f2bf(v0.x) | (f2bf(v0.y) << 16);
        pk.y = f2bf(v0.z) | (f2bf(v0.w) << 16);
        pk.z = f2bf(v1.x) | (f2bf(v1.y) << 16);
        pk.w = f2bf(v1.z) | (f2bf(v1.w) << 16);
        int byte = (row * 256 + ks * 16) ^ ((row & 7) << 4);
        *reinterpret_cast<uint4*>(reinterpret_cast<char*>(albuf) + byte) = pk;
    }
    __syncthreads();

    const int lane = tid & 63, wid = tid >> 6;
    const int f0 = wid * 64;
    const int lr = lane & 15, lg = lane >> 4;

    f32x4 acc[8][4];
    #pragma unroll
    for (int m = 0; m < 8; ++m)
        #pragma unroll
        for (int ft = 0; ft < 4; ++ft)
            acc[m][ft] = (f32x4){0.f, 0.f, 0.f, 0.f};

    // NOTE: linear bias b is absorbed by BN (mean shifts by b, (x-mean) cancels) -> skipped.
    #pragma unroll
    for (int kt = 0; kt < 4; ++kt) {
        short8 bfr[4];
        #pragma unroll
        for (int ft = 0; ft < 4; ++ft)   // B-frag: col = lr, k = kt*32 + lg*8 + j  (W row-major, L2-resident)
            bfr[ft] = *reinterpret_cast<const short8*>(
                Wb + (size_t)(f0 + ft * 16 + lr) * NA_ + kt * 32 + lg * 8);
        #pragma unroll
        for (int m = 0; m < 8; ++m) {
            int row = m * 16 + lr;                 // A-frag: row = lr, k = kt*32 + lg*8 + j
            int byte = (row * 256 + kt * 64 + lg * 16) ^ ((row & 7) << 4);
            short8 afr = *reinterpret_cast<const short8*>(
                reinterpret_cast<const char*>(albuf) + byte);
            #pragma unroll
            for (int ft = 0; ft < 4; ++ft)
                acc[m][ft] = __builtin_amdgcn_mfma_f32_16x16x32_bf16(afr, bfr[ft], acc[m][ft], 0, 0, 0);
        }
    }

    // ---- BN stats per feature (cols owned per-lane), fold to scale/shift, write x bf16
    #pragma unroll
    for (int ft = 0; ft < 4; ++ft) {
        float s = 0.f, q = 0.f;
        #pragma unroll
        for (int m = 0; m < 8; ++m)
            #pragma unroll
            for (int r = 0; r < 4; ++r) {
                float v = acc[m][ft][r];
                s += v; q = fmaf(v, v, q);
            }
        s += __shfl_xor(s, 16, 64); s += __shfl_xor(s, 32, 64);
        q += __shfl_xor(q, 16, 64); q += __shfl_xor(q, 32, 64);
        const int f = f0 + ft * 16 + lr;
        float mean = s * (1.f / VBS_);
        float var  = q * (1.f / VBS_) - mean * mean;
        float rs = rsqrtf(var + EPS_) * bnw[f];
        float sh = fmaf(-mean, rs, bnb[f]);
        if (lg == 0) {
            scale_g[chunk * F_ + f] = rs;
            shift_g[chunk * F_ + f] = sh;
        }
        #pragma unroll
        for (int m = 0; m < 8; ++m)
            #pragma unroll
            for (int r = 0; r < 4; ++r) {
                int row = m * 16 + lg * 4 + r;     // C/D: col=lr, row=4*lg+reg (m89-verified)
                xb[(rowbase + row) * F_ + f] = (unsigned short)f2bf(acc[m][ft][r]);
            }
    }
}

// ---------------- kernel 2: streaming BN-apply + sparsemax + outputs (wave per row) ----------------
__global__ __launch_bounds__(256, 4) void k2_sparsemax(
    const unsigned short* __restrict__ xb, const float* __restrict__ prior,
    const float* __restrict__ scale_g, const float* __restrict__ shift_g,
    float* __restrict__ out_m, float* __restrict__ out_np)
{
    __shared__ float srt[4][F_];                   // slow-path only
    const int lane = threadIdx.x & 63, wid = threadIdx.x >> 6;
    const size_t row = (size_t)blockIdx.x * 4 + wid;
    const int chunk = (int)(row >> 7);
    const size_t base = row * F_;

    uint2 xu = *reinterpret_cast<const uint2*>(xb + base + lane * 4);
    float4 p  = reinterpret_cast<const float4*>(prior + base)[lane];
    float4 sc = reinterpret_cast<const float4*>(scale_g + (size_t)chunk * F_)[lane];
    float4 sh = reinterpret_cast<const float4*>(shift_g + (size_t)chunk * F_)[lane];

    float z0 = fmaf(bflo(xu.x), sc.x, sh.x) * p.x;
    float z1 = fmaf(bfhi(xu.x), sc.y, sh.y) * p.y;
    float z2 = fmaf(bflo(xu.y), sc.z, sh.z) * p.z;
    float z3 = fmaf(bfhi(xu.y), sc.w, sh.w) * p.w;

    float s  = (z0 + z1) + (z2 + z3);
    float mx = fmaxf(fmaxf(z0, z1), fmaxf(z2, z3));
    #pragma unroll
    for (int d = 1; d < 64; d <<= 1) {
        s += __shfl_xor(s, d, 64);
        mx = fmaxf(mx, __shfl_xor(mx, d, 64));
    }

    float tau;
    if (1.0f + 255.0f * mx - s > 0.0f) {
        // w[255] true -> k_z = 255, m_z = full sum (fast path; ~always taken for BN'd data)
        tau = (s + 1.0f) * (1.0f / 255.0f);
    } else {
        // faithful sorted algorithm, wave-uniform branch, lane-0 serial (rare/never)
        float* sr = srt[wid];
        sr[lane * 4 + 0] = z0; sr[lane * 4 + 1] = z1;
        sr[lane * 4 + 2] = z2; sr[lane * 4 + 3] = z3;
        __asm__ volatile("s_waitcnt lgkmcnt(0)" ::: "memory");
        float t0 = 0.f;
        if (lane == 0) {
            for (int i = 1; i < F_; ++i) {         // insertion sort ascending
                float key = sr[i]; int j = i - 1;
                while (j >= 0 && sr[j] > key) { sr[j + 1] = sr[j]; --j; }
                sr[j + 1] = key;
            }
            float cs = 0.f; int kz = 0;
            for (int j = 0; j < F_; ++j) {
                cs += sr[j];
                if (1.0f + (float)j * sr[j] - cs > 0.0f) kz = j;
            }
            float mz = 0.f;
            for (int j = 0; j <= kz; ++j) mz += sr[j];
            t0 = (mz + 1.0f) / (float)kz;          // kz==0 -> inf -> m=0, matches clip
        }
        tau = __shfl(t0, 0, 64);
    }

    float m0 = fmaxf(z0 - tau, 0.f), m1 = fmaxf(z1 - tau, 0.f);
    float m2 = fmaxf(z2 - tau, 0.f), m3 = fmaxf(z3 - tau, 0.f);
    float4 om = {m0, m1, m2, m3};
    float4 on = {p.x * (GAMMA_ - m0), p.y * (GAMMA_ - m1),
                 p.z * (GAMMA_ - m2), p.w * (GAMMA_ - m3)};
    reinterpret_cast<float4*>(out_m  + base)[lane] = om;
    reinterpret_cast<float4*>(out_np + base)[lane] = on;
}

// ---------------- fallback: round-1 fused kernel (used only if ws too small) ----------------
__global__ __launch_bounds__(256, 1) void attn_fused(
    const float* __restrict__ a, const float* __restrict__ prior,
    const float* __restrict__ W, const float* __restrict__ bias,
    const float* __restrict__ bnw, const float* __restrict__ bnb,
    float* __restrict__ out_m, float* __restrict__ out_np)
{
    __shared__ float zbuf[VBS_ * F_];
    __shared__ float astage[32 * NA_];
    __shared__ float tau_s[VBS_];
    __shared__ float scale_s[F_];
    __shared__ float shift_s[F_];
    __shared__ float srt[F_];
    __shared__ int nflag;

    const int tid = threadIdx.x;
    const int f = tid;
    const int chunk = blockIdx.x;
    const size_t rowbase = (size_t)chunk * VBS_;
    if (tid == 0) nflag = 0;

    float4 w4[NA_ / 4];
    {
        const float4* wrow = reinterpret_cast<const float4*>(W + (size_t)f * NA_);
        #pragma unroll
        for (int i = 0; i < NA_ / 4; ++i) w4[i] = wrow[i];
    }
    const float bf = bias[f];

    for (int q = 0; q < 4; ++q) {
        __syncthreads();
        {
            const float4* ag = reinterpret_cast<const float4*>(a + (rowbase + (size_t)q * 32) * NA_);
            float4* as4 = reinterpret_cast<float4*>(astage);
            for (int idx = tid; idx < 32 * NA_ / 4; idx += 256) as4[idx] = ag[idx];
        }
        __syncthreads();
        for (int rr = 0; rr < 32; ++rr) {
            const float4* arow = reinterpret_cast<const float4*>(astage + rr * NA_);
            float acc0 = bf, acc1 = 0.f, acc2 = 0.f, acc3 = 0.f;
            #pragma unroll
            for (int kk = 0; kk < NA_ / 4; ++kk) {
                float4 av = arow[kk];
                acc0 = fmaf(av.x, w4[kk].x, acc0);
                acc1 = fmaf(av.y, w4[kk].y, acc1);
                acc2 = fmaf(av.z, w4[kk].z, acc2);
                acc3 = fmaf(av.w, w4[kk].w, acc3);
            }
            zbuf[(q * 32 + rr) * F_ + f] = (acc0 + acc1) + (acc2 + acc3);
        }
    }
    __syncthreads();
    {
        float s0 = 0, q0 = 0;
        for (int r = 0; r < VBS_; ++r) {
            float v = zbuf[r * F_ + f];
            s0 += v; q0 = fmaf(v, v, q0);
        }
        float mean = s0 * (1.0f / VBS_);
        float var  = q0 * (1.0f / VBS_) - mean * mean;
        float rs = rsqrtf(var + EPS_) * bnw[f];
        scale_s[f] = rs;
        shift_s[f] = bnb[f] - mean * rs;
    }
    __syncthreads();
    {
        const int rsub = tid >> 6, c4 = tid & 63;
        float4 sc = reinterpret_cast<const float4*>(scale_s)[c4];
        float4 shv = reinterpret_cast<const float4*>(shift_s)[c4];
        for (int i = 0; i < VBS_ / 4; ++i) {
            int r = i * 4 + rsub;
            float4 x4 = reinterpret_cast<float4*>(zbuf)[r * (F_ / 4) + c4];
            float4 p4 = reinterpret_cast<const float4*>(prior + (rowbase + r) * F_)[c4];
            float4 z;
            z.x = fmaf(x4.x, sc.x, shv.x) * p4.x;
            z.y = fmaf(x4.y, sc.y, shv.y) * p4.y;
            z.z = fmaf(x4.z, sc.z, shv.z) * p4.z;
            z.w = fmaf(x4.w, sc.w, shv.w) * p4.w;
            reinterpret_cast<float4*>(zbuf)[r * (F_ / 4) + c4] = z;
        }
    }
    __syncthreads();
    {
        const int wv = tid >> 6, lane = tid & 63;
        for (int r = wv * 32; r < wv * 32 + 32; ++r) {
            float v0 = zbuf[r * F_ + lane];
            float v1 = zbuf[r * F_ + lane + 64];
            float v2 = zbuf[r * F_ + lane + 128];
            float v3 = zbuf[r * F_ + lane + 192];
            float s = (v0 + v1) + (v2 + v3);
            float mx = fmaxf(fmaxf(v0, v1), fmaxf(v2, v3));
            #pragma unroll
            for (int d = 32; d > 0; d >>= 1) {
                s += __shfl_xor(s, d, 64);
                mx = fmaxf(mx, __shfl_xor(mx, d, 64));
            }
            if (lane == 0) {
                if (1.0f + 255.0f * mx - s > 0.0f) {
                    tau_s[r] = (s + 1.0f) * (1.0f / 255.0f);
                } else {
                    tau_s[r] = __int_as_float(0x7fc00000);
                    atomicAdd(&nflag, 1);
                }
            }
        }
    }
    __syncthreads();
    if (nflag > 0) {
        for (int r = 0; r < VBS_; ++r) {
            float tv = tau_s[r];
            if (!(tv != tv)) continue;
            if (tid == 0) {
                for (int i = 0; i < F_; ++i) srt[i] = zbuf[r * F_ + i];
                for (int i = 1; i < F_; ++i) {
                    float key = srt[i]; int j = i - 1;
                    while (j >= 0 && srt[j] > key) { srt[j + 1] = srt[j]; --j; }
                    srt[j + 1] = key;
                }
                float cs = 0.f; int kz = 0;
                for (int j = 0; j < F_; ++j) {
                    cs += srt[j];
                    if (1.0f + (float)j * srt[j] - cs > 0.0f) kz = j;
                }
                float mz = 0.f;
                for (int j = 0; j <= kz; ++j) mz += srt[j];
                tau_s[r] = (mz + 1.0f) / (float)kz;
            }
            __syncthreads();
        }
    }
    __syncthreads();
    {
        const int rsub = tid >> 6, c4 = tid & 63;
        for (int i = 0; i < VBS_ / 4; ++i) {
            int r = i * 4 + rsub;
            float tau = tau_s[r];
            float4 z4 = reinterpret_cast<float4*>(zbuf)[r * (F_ / 4) + c4];
            float4 p4 = reinterpret_cast<const float4*>(prior + (rowbase + r) * F_)[c4];
            float4 m4, n4;
            m4.x = fmaxf(z4.x - tau, 0.0f); n4.x = p4.x * (GAMMA_ - m4.x);
            m4.y = fmaxf(z4.y - tau, 0.0f); n4.y = p4.y * (GAMMA_ - m4.y);
            m4.z = fmaxf(z4.z - tau, 0.0f); n4.z = p4.z * (GAMMA_ - m4.z);
            m4.w = fmaxf(z4.w - tau, 0.0f); n4.w = p4.w * (GAMMA_ - m4.w);
            reinterpret_cast<float4*>(out_m + (rowbase + r) * F_)[c4] = m4;
            reinterpret_cast<float4*>(out_np + (rowbase + r) * F_)[c4] = n4;
        }
    }
}

extern "C" void kernel_launch(void* const* d_in, const int* in_sizes, int n_in,
                              void* d_out, int out_size, void* d_ws, size_t ws_size,
                              hipStream_t stream) {
    const float* a     = (const float*)d_in[0];
    const float* prior = (const float*)d_in[1];
    const float* W     = (const float*)d_in[2];
    const float* b     = (const float*)d_in[3];
    const float* bnw   = (const float*)d_in[4];
    const float* bnb   = (const float*)d_in[5];
    const int N = in_sizes[0] / NA_;
    const int nchunks = N / VBS_;
    float* out_m  = (float*)d_out;
    float* out_np = out_m + (size_t)N * F_;

    size_t xbytes  = (size_t)N * F_ * 2;            // x bf16
    size_t ssbytes = (size_t)nchunks * F_ * 4;      // scale / shift f32 each
    size_t need    = xbytes + 2 * ssbytes + (size_t)F_ * NA_ * 2;

    if (ws_size >= need) {
        unsigned short* xbuf    = (unsigned short*)d_ws;
        float* scale_g          = (float*)((char*)d_ws + xbytes);
        float* shift_g          = (float*)((char*)d_ws + xbytes + ssbytes);
        unsigned short* Wb      = (unsigned short*)((char*)d_ws + xbytes + 2 * ssbytes);
        k0_cvt_w<<<(F_ * NA_ / 4 + 255) / 256, 256, 0, stream>>>(W, Wb);
        k1_gemm_stats<<<nchunks, 256, 0, stream>>>(a, Wb, bnw, bnb, xbuf, scale_g, shift_g);
        k2_sparsemax<<<N / 4, 256, 0, stream>>>(xbuf, prior, scale_g, shift_g, out_m, out_np);
    } else {
        attn_fused<<<nchunks, 256, 0, stream>>>(a, prior, W, b, bnw, bnb, out_m, out_np);
    }
}